// Round 4
// baseline (135294.568 us; speedup 1.0000x reference)
//
#include <hip/hip_runtime.h>
#include <hip/hip_cooperative_groups.h>
#include <math.h>

namespace cg = cooperative_groups;

namespace {
constexpr int BATCH = 128;
constexpr int SEQ   = 512;
constexpr int NL    = 32;
constexpr int BOSTAG = 1;
constexpr int EOSTAG = 2;
}

// hbuf layout: [2 parity][2 dir][128 b][512 u]  (65536 floats per (par,dir))
__global__ __launch_bounds__(512, 1)
void bilstm_coop(const int* __restrict__ x,
                 const float* __restrict__ emb,
                 const float* __restrict__ Wih_f, const float* __restrict__ Whh_f, const float* __restrict__ bf,
                 const float* __restrict__ Wih_b, const float* __restrict__ Whh_b, const float* __restrict__ bbias,
                 const float* __restrict__ Wout, const float* __restrict__ bout,
                 float* __restrict__ hbuf, float* __restrict__ em)
{
  cg::grid_group grid = cg::this_grid();
  __shared__ float4 WT4[8192];     // [k(1024)][slot(8)], slot = uu ^ ((k>>2)&7), inner = gate. 128 KB
  __shared__ float  em_red[512];   // [eks(16)][l(32)]
  float* WTf = (float*)WT4;

  const int tid = threadIdx.x, bi = blockIdx.x;
  const int dir = bi >> 7, bidx = bi & 127;
  const int ug  = bidx >> 1, bh = bidx & 1;    // ug: 8-unit slice, bh: batch half
  const int u0  = ug * 8, b_base = bh * 64;
  const int bb  = b_base + ug;                 // emission batch owned by this block

  const float* Wih = dir ? Wih_b : Wih_f;
  const float* Whh = dir ? Whh_b : Whh_f;
  const float* bv  = dir ? bbias : bf;

  // ---- one-time: W slice -> LDS, [k][uu^((k>>2)&7)][gate] ----
  for (int idx = tid; idx < 32768; idx += 512) {
    const int k = idx >> 5, r = idx & 31;
    const int gate = r & 3, uu = r >> 2;
    const int grow = gate * 512 + u0 + uu;
    const float v = (k < 512) ? Wih[(size_t)grow * 512 + k]
                              : Whh[(size_t)grow * 512 + (k - 512)];
    WTf[k * 32 + ((uu ^ ((k >> 2) & 7)) << 2) + gate] = v;
  }

  // compute mapping: thread = (ks, bown); owns k-slice {ks*4+32i+j} and batch bown
  const int ks   = tid & 7;
  const int bown = tid >> 3;
  const int bg   = b_base + bown;
  // emission mapping
  const int el = tid & 31, eks = tid >> 5;

  float bias_g[4];
  #pragma unroll
  for (int g = 0; g < 4; ++g) bias_g[g] = bv[g * 512 + u0 + ks];

  float wout_r[32];
  #pragma unroll
  for (int ch = 0; ch < 16; ++ch) {
    wout_r[ch * 2 + 0] = Wout[(size_t)el * 1024 + dir * 512 + ch * 32 + eks * 2 + 0];
    wout_r[ch * 2 + 1] = Wout[(size_t)el * 1024 + dir * 512 + ch * 32 + eks * 2 + 1];
  }
  float cstate = 0.f;

  // zero parity-1 h (initial state for s=0)
  hbuf[131072 + bi * 512 + tid] = 0.f;
  grid.sync();

  for (int s = 0; s < SEQ; ++s) {
    const int t = dir ? (SEQ - 1 - s) : s;

    // ---- issue emb gathers BEFORE grid.sync (sync hides the latency) ----
    const int xid = x[bg * SEQ + t];
    const float* er = emb + (size_t)xid * 512 + ks * 4;
    float4 ae[16];
    #pragma unroll
    for (int i = 0; i < 16; ++i) ae[i] = *(const float4*)&er[32 * i];

    grid.sync();

    const float* hprev = hbuf + (size_t)((s + 1) & 1) * 131072 + dir * 65536;
    float*       hout  = hbuf + (size_t)((s    ) & 1) * 131072 + dir * 65536;

    // ---- issue emission h loads (for h_{s-1}) + recurrent h loads ----
    float2 eh[16];
    if (s > 0) {
      const float* hb_ = hprev + (size_t)bb * 512;
      #pragma unroll
      for (int ch = 0; ch < 16; ++ch)
        eh[ch] = *(const float2*)&hb_[ch * 32 + eks * 2];
    }
    float4 ah[16];
    {
      const float* hr = hprev + (size_t)bg * 512 + ks * 4;
      #pragma unroll
      for (int i = 0; i < 16; ++i) ah[i] = *(const float4*)&hr[32 * i];
    }

    // ---- emission partial (frees eh before the h-FMA wall) ----
    float emP = 0.f;
    if (s > 0) {
      #pragma unroll
      for (int ch = 0; ch < 16; ++ch) {
        emP = fmaf(eh[ch].x, wout_r[ch * 2 + 0], emP);
        emP = fmaf(eh[ch].y, wout_r[ch * 2 + 1], emP);
      }
    }

    float acc[8][4];
    #pragma unroll
    for (int uu = 0; uu < 8; ++uu)
      #pragma unroll
      for (int g = 0; g < 4; ++g) acc[uu][g] = 0.f;

    // ---- emb part: k in [0,512) ----
    #pragma unroll
    for (int i = 0; i < 16; ++i) {
      const float av[4] = {ae[i].x, ae[i].y, ae[i].z, ae[i].w};
      #pragma unroll
      for (int j = 0; j < 4; ++j) {
        const float a = av[j];
        const float4* Wk = WT4 + (size_t)(ks * 4 + 32 * i + j) * 8;
        #pragma unroll
        for (int uu = 0; uu < 8; ++uu) {
          const float4 w4 = Wk[uu ^ ks];
          acc[uu][0] = fmaf(w4.x, a, acc[uu][0]);
          acc[uu][1] = fmaf(w4.y, a, acc[uu][1]);
          acc[uu][2] = fmaf(w4.z, a, acc[uu][2]);
          acc[uu][3] = fmaf(w4.w, a, acc[uu][3]);
        }
      }
    }
    // ---- h part: k in [512,1024) ----
    #pragma unroll
    for (int i = 0; i < 16; ++i) {
      const float av[4] = {ah[i].x, ah[i].y, ah[i].z, ah[i].w};
      #pragma unroll
      for (int j = 0; j < 4; ++j) {
        const float a = av[j];
        const float4* Wk = WT4 + (size_t)(512 + ks * 4 + 32 * i + j) * 8;
        #pragma unroll
        for (int uu = 0; uu < 8; ++uu) {
          const float4 w4 = Wk[uu ^ ks];
          acc[uu][0] = fmaf(w4.x, a, acc[uu][0]);
          acc[uu][1] = fmaf(w4.y, a, acc[uu][1]);
          acc[uu][2] = fmaf(w4.z, a, acc[uu][2]);
          acc[uu][3] = fmaf(w4.w, a, acc[uu][3]);
        }
      }
    }

    // ---- emission reduce + write for step s-1 ----
    if (s > 0) em_red[eks * 32 + el] = emP;
    __syncthreads();
    if (s > 0 && tid < 32) {
      float p = 0.f;
      #pragma unroll
      for (int ksi = 0; ksi < 16; ++ksi) p += em_red[ksi * 32 + tid];
      const int te = dir ? (SEQ - s) : (s - 1);
      const bool first = dir ? (te >= 256) : (te < 256);
      float* dst = em + ((size_t)bb * SEQ + te) * NL + tid;
      if (first) *dst = p + bout[tid];
      else       *dst = *dst + p;
    }

    // ---- butterfly over the 8 ks lanes (in-wave xor 1,2,4) ----
    #pragma unroll
    for (int m = 1; m < 8; m <<= 1)
      #pragma unroll
      for (int uu = 0; uu < 8; ++uu)
        #pragma unroll
        for (int g = 0; g < 4; ++g)
          acc[uu][g] += __shfl_xor(acc[uu][g], m, 64);

    // lane ks owns unit u0+ks: static ternary select (no runtime reg index)
    {
      float g4[4];
      #pragma unroll
      for (int g = 0; g < 4; ++g) {
        float v = acc[0][g];
        v = (ks == 1) ? acc[1][g] : v;
        v = (ks == 2) ? acc[2][g] : v;
        v = (ks == 3) ? acc[3][g] : v;
        v = (ks == 4) ? acc[4][g] : v;
        v = (ks == 5) ? acc[5][g] : v;
        v = (ks == 6) ? acc[6][g] : v;
        v = (ks == 7) ? acc[7][g] : v;
        g4[g] = v;
      }
      const float gi = g4[0] + bias_g[0];
      const float gf = g4[1] + bias_g[1];
      const float gg = g4[2] + bias_g[2];
      const float go = g4[3] + bias_g[3];
      const float si = 1.f / (1.f + expf(-gi));
      const float sf = 1.f / (1.f + expf(-gf));
      const float so = 1.f / (1.f + expf(-go));
      cstate = sf * cstate + si * tanhf(gg);
      hout[(size_t)bg * 512 + u0 + ks] = so * tanhf(cstate);
    }
  }
  grid.sync();

  // ---- tail emission for the last h (s=511 -> parity 1) ----
  {
    const float* hb_ = hbuf + 131072 + dir * 65536 + (size_t)bb * 512;
    float emP = 0.f;
    #pragma unroll
    for (int ch = 0; ch < 16; ++ch) {
      const float2 hv = *(const float2*)&hb_[ch * 32 + eks * 2];
      emP = fmaf(hv.x, wout_r[ch * 2 + 0], emP);
      emP = fmaf(hv.y, wout_r[ch * 2 + 1], emP);
    }
    em_red[eks * 32 + el] = emP;
    __syncthreads();
    if (tid < 32) {
      float p = 0.f;
      #pragma unroll
      for (int ksi = 0; ksi < 16; ++ksi) p += em_red[ksi * 32 + tid];
      const int te = dir ? 0 : (SEQ - 1);
      float* dst = em + ((size_t)bb * SEQ + te) * NL + tid;
      *dst = *dst + p;
    }
  }
}

__global__ __launch_bounds__(64)
void viterbi_kernel(const float* __restrict__ em, const int* __restrict__ mask,
                    const float* __restrict__ trans, float* __restrict__ out)
{
  __shared__ float tr[32][33];
  __shared__ float alpha[32];
  __shared__ float fin[32];
  __shared__ unsigned char bp[SEQ][32];
  __shared__ float path[SEQ];

  const int b = blockIdx.x, tid = threadIdx.x;
  for (int i = tid; i < 1024; i += 64) tr[i >> 5][i & 31] = trans[i];
  __syncthreads();

  const float* emB = em + (size_t)b * SEQ * NL;
  if (tid < 32) alpha[tid] = tr[BOSTAG][tid] + emB[tid];
  __syncthreads();

  for (int t = 1; t < SEQ; ++t) {
    float best = -INFINITY, e = 0.f;
    int arg = 0;
    if (tid < 32) {
      e = emB[t * NL + tid];
      #pragma unroll 4
      for (int p = 0; p < 32; ++p) {
        const float sc = (alpha[p] + tr[p][tid]) + e;  // np broadcast order
        if (sc > best) { best = sc; arg = p; }          // first-occurrence argmax
      }
    }
    __syncthreads();
    if (tid < 32) {
      const float m = (float)mask[b * SEQ + t];
      alpha[tid] = m * best + (1.f - m) * alpha[tid];
      bp[t][tid] = (unsigned char)arg;
    }
    __syncthreads();
  }

  if (tid < 32) fin[tid] = alpha[tid] + tr[tid][EOSTAG];
  __syncthreads();

  if (tid == 0) {
    float best = fin[0]; int tag = 0;
    for (int n = 1; n < 32; ++n) if (fin[n] > best) { best = fin[n]; tag = n; }
    out[b] = best;
    path[SEQ - 1] = (float)tag;
    for (int k = SEQ - 2; k >= 0; --k) {
      const int prev = bp[k + 1][tag];
      if (mask[b * SEQ + k + 1] > 0) tag = prev;
      path[k] = (float)tag;
    }
  }
  __syncthreads();
  for (int idx = tid; idx < SEQ; idx += 64)
    out[BATCH + (size_t)b * SEQ + idx] = path[idx];
}

extern "C" void kernel_launch(void* const* d_in, const int* in_sizes, int n_in,
                              void* d_out, int out_size, void* d_ws, size_t ws_size,
                              hipStream_t stream) {
  (void)in_sizes; (void)n_in; (void)out_size; (void)ws_size;
  const int*   x     = (const int*)d_in[0];
  const int*   mask  = (const int*)d_in[1];
  const float* emb   = (const float*)d_in[2];
  const float* Wih_f = (const float*)d_in[3];
  const float* Whh_f = (const float*)d_in[4];
  const float* bf    = (const float*)d_in[5];
  const float* Wih_b = (const float*)d_in[6];
  const float* Whh_b = (const float*)d_in[7];
  const float* bb    = (const float*)d_in[8];
  const float* Wout  = (const float*)d_in[9];
  const float* bout  = (const float*)d_in[10];
  const float* trans = (const float*)d_in[11];
  float* out  = (float*)d_out;
  float* hbuf = (float*)d_ws;                   // 262144 floats (1 MB)
  float* em   = hbuf + 262144;                  // 2097152 floats (8 MB)

  void* args[] = { (void*)&x, (void*)&emb,
                   (void*)&Wih_f, (void*)&Whh_f, (void*)&bf,
                   (void*)&Wih_b, (void*)&Whh_b, (void*)&bb,
                   (void*)&Wout, (void*)&bout,
                   (void*)&hbuf, (void*)&em };
  hipLaunchCooperativeKernel((void*)bilstm_coop, dim3(256), dim3(512), args, 0, stream);
  viterbi_kernel<<<dim3(128), dim3(64), 0, stream>>>(em, mask, trans, out);
}

// Round 5
// 28548.102 us; speedup vs baseline: 4.7392x; 4.7392x over previous
//
#include <hip/hip_runtime.h>
#include <hip/hip_cooperative_groups.h>
#include <math.h>

namespace cg = cooperative_groups;

namespace {
constexpr int BATCH = 128;
constexpr int SEQ   = 512;
constexpr int NL    = 32;
constexpr int BOSTAG = 1;
constexpr int EOSTAG = 2;
}

// hbuf layout: [2 parity][2 dir][128 b][512 u]  (65536 floats per (par,dir))
__global__ __launch_bounds__(512, 2)
void bilstm_coop(const int* __restrict__ x,
                 const float* __restrict__ emb,
                 const float* __restrict__ Wih_f, const float* __restrict__ Whh_f, const float* __restrict__ bf,
                 const float* __restrict__ Wih_b, const float* __restrict__ Whh_b, const float* __restrict__ bbias,
                 const float* __restrict__ Wout, const float* __restrict__ bout,
                 float* __restrict__ hbuf, float* __restrict__ em)
{
  cg::grid_group grid = cg::this_grid();
  __shared__ float4 WT4[8192];     // [k(1024)][slot(8)] gates in .xyzw; slot = uu ^ ((k>>2)&7). 128 KB
  __shared__ float  em_red[512];   // [eks(16)][l(32)]

  const int tid = threadIdx.x, bi = blockIdx.x;
  const int dir = bi >> 7, bidx = bi & 127;
  const int ug  = bidx >> 1, bh = bidx & 1;    // ug: 8-unit slice, bh: batch half
  const int u0  = ug * 8, b_base = bh * 64;
  const int bb  = b_base + ug;                 // emission batch owned by this block

  const float* Wih = dir ? Wih_b : Wih_f;
  const float* Whh = dir ? Whh_b : Whh_f;
  const float* bv  = dir ? bbias : bf;

  // ---- one-time: W slice -> LDS. WT4[k*8+slot] = gates(i,f,g,o) of unit uu=slot^((k>>2)&7)
  for (int idx = tid; idx < 8192; idx += 512) {
    const int k = idx >> 3, slot = idx & 7;
    const int uu = slot ^ ((k >> 2) & 7);
    float4 v;
    if (k < 512) {
      v.x = Wih[(size_t)(0 * 512 + u0 + uu) * 512 + k];
      v.y = Wih[(size_t)(1 * 512 + u0 + uu) * 512 + k];
      v.z = Wih[(size_t)(2 * 512 + u0 + uu) * 512 + k];
      v.w = Wih[(size_t)(3 * 512 + u0 + uu) * 512 + k];
    } else {
      v.x = Whh[(size_t)(0 * 512 + u0 + uu) * 512 + (k - 512)];
      v.y = Whh[(size_t)(1 * 512 + u0 + uu) * 512 + (k - 512)];
      v.z = Whh[(size_t)(2 * 512 + u0 + uu) * 512 + (k - 512)];
      v.w = Whh[(size_t)(3 * 512 + u0 + uu) * 512 + (k - 512)];
    }
    WT4[idx] = v;
  }

  // compute mapping: thread = (ks in-wave k-split, bown batch)
  const int ks   = tid & 7;
  const int bown = tid >> 3;
  const int bg   = b_base + bown;
  // emission mapping
  const int el = tid & 31, eks = tid >> 5;     // label, k-split of 16 (32 k each)

  float bias_g[4];
  #pragma unroll
  for (int g = 0; g < 4; ++g) bias_g[g] = bv[g * 512 + u0 + ks];
  float cstate = 0.f;

  // zero parity-1 h (initial state)
  hbuf[131072 + bi * 512 + tid] = 0.f;
  grid.sync();

  for (int s = 0; s < SEQ; ++s) {
    const int t = dir ? (SEQ - 1 - s) : s;
    // pre-sync: only xid + first A float4 held across the sync (cheap)
    const int    xid  = x[bg * SEQ + t];
    const float* erow = emb + (size_t)xid * 512 + ks * 4;
    float4 aP = *(const float4*)erow;

    grid.sync();

    const float* hprev = hbuf + (size_t)((s + 1) & 1) * 131072 + dir * 65536;
    float*       hout  = hbuf + (size_t)((s    ) & 1) * 131072 + dir * 65536;
    const float* hrow  = hprev + (size_t)bg * 512 + ks * 4;

    // ---- emission for h_{s-1} (acc not yet live; wv/hv transient) ----
    if (s > 0) {
      const float* wr_ = Wout + (size_t)el * 1024 + dir * 512 + eks * 32;
      const float* hb2 = hprev + (size_t)bb * 512 + eks * 32;
      float4 wv[8], hv[8];
      #pragma unroll
      for (int q = 0; q < 8; ++q) wv[q] = *(const float4*)&wr_[q * 4];
      #pragma unroll
      for (int q = 0; q < 8; ++q) hv[q] = *(const float4*)&hb2[q * 4];
      float emP = 0.f;
      #pragma unroll
      for (int q = 0; q < 8; ++q) {
        emP = fmaf(hv[q].x, wv[q].x, emP);
        emP = fmaf(hv[q].y, wv[q].y, emP);
        emP = fmaf(hv[q].z, wv[q].z, emP);
        emP = fmaf(hv[q].w, wv[q].w, emP);
      }
      em_red[eks * 32 + el] = emP;
    }
    __syncthreads();
    if (s > 0 && tid < 32) {
      float p = 0.f;
      #pragma unroll
      for (int ksi = 0; ksi < 16; ++ksi) p += em_red[ksi * 32 + tid];
      const int te = dir ? (SEQ - s) : (s - 1);
      const bool first = dir ? (te >= 256) : (te < 256);
      float* dst = em + ((size_t)bb * SEQ + te) * NL + tid;
      if (first) *dst = p + bout[tid];
      else       *dst = *dst + p;
    }

    // ---- gate GEMM: acc[uu][g], k-split over 8 in-wave lanes ----
    float acc[8][4];
    #pragma unroll
    for (int uu = 0; uu < 8; ++uu)
      #pragma unroll
      for (int g = 0; g < 4; ++g) acc[uu][g] = 0.f;

    // emb half: k = ks*4 + 32i + j
    #pragma unroll 2
    for (int i = 0; i < 16; ++i) {
      const float4 aC = aP;
      const float* nx = (i < 15) ? (erow + 32 * (i + 1)) : hrow;
      aP = *(const float4*)nx;
      const float4* Wb = WT4 + (size_t)(ks * 4 + 32 * i) * 8;
      #pragma unroll
      for (int j = 0; j < 4; ++j) {
        const float a = (j == 0) ? aC.x : (j == 1) ? aC.y : (j == 2) ? aC.z : aC.w;
        const float4* Wk = Wb + j * 8;
        #pragma unroll
        for (int uu = 0; uu < 8; ++uu) {
          const float4 w4 = Wk[uu ^ ks];
          acc[uu][0] = fmaf(w4.x, a, acc[uu][0]);
          acc[uu][1] = fmaf(w4.y, a, acc[uu][1]);
          acc[uu][2] = fmaf(w4.z, a, acc[uu][2]);
          acc[uu][3] = fmaf(w4.w, a, acc[uu][3]);
        }
      }
    }
    // h half: k = 512 + ks*4 + 32i + j
    #pragma unroll 2
    for (int i = 0; i < 16; ++i) {
      const float4 aC = aP;
      const float* nx = (i < 15) ? (hrow + 32 * (i + 1)) : erow;  // last: dummy safe prefetch
      aP = *(const float4*)nx;
      const float4* Wb = WT4 + (size_t)(512 + ks * 4 + 32 * i) * 8;
      #pragma unroll
      for (int j = 0; j < 4; ++j) {
        const float a = (j == 0) ? aC.x : (j == 1) ? aC.y : (j == 2) ? aC.z : aC.w;
        const float4* Wk = Wb + j * 8;
        #pragma unroll
        for (int uu = 0; uu < 8; ++uu) {
          const float4 w4 = Wk[uu ^ ks];
          acc[uu][0] = fmaf(w4.x, a, acc[uu][0]);
          acc[uu][1] = fmaf(w4.y, a, acc[uu][1]);
          acc[uu][2] = fmaf(w4.z, a, acc[uu][2]);
          acc[uu][3] = fmaf(w4.w, a, acc[uu][3]);
        }
      }
    }

    // ---- butterfly over the 8 ks lanes (in-wave xor 1,2,4) ----
    #pragma unroll
    for (int m = 1; m < 8; m <<= 1)
      #pragma unroll
      for (int uu = 0; uu < 8; ++uu)
        #pragma unroll
        for (int g = 0; g < 4; ++g)
          acc[uu][g] += __shfl_xor(acc[uu][g], m, 64);

    // lane ks owns unit u0+ks: static ternary select
    {
      float g4[4];
      #pragma unroll
      for (int g = 0; g < 4; ++g) {
        float v = acc[0][g];
        v = (ks == 1) ? acc[1][g] : v;
        v = (ks == 2) ? acc[2][g] : v;
        v = (ks == 3) ? acc[3][g] : v;
        v = (ks == 4) ? acc[4][g] : v;
        v = (ks == 5) ? acc[5][g] : v;
        v = (ks == 6) ? acc[6][g] : v;
        v = (ks == 7) ? acc[7][g] : v;
        g4[g] = v;
      }
      const float gi = g4[0] + bias_g[0];
      const float gf = g4[1] + bias_g[1];
      const float gg = g4[2] + bias_g[2];
      const float go = g4[3] + bias_g[3];
      const float si = 1.f / (1.f + expf(-gi));
      const float sf = 1.f / (1.f + expf(-gf));
      const float so = 1.f / (1.f + expf(-go));
      cstate = sf * cstate + si * tanhf(gg);
      hout[(size_t)bg * 512 + u0 + ks] = so * tanhf(cstate);
    }
  }
  grid.sync();

  // ---- tail emission for the last h (parity 1) ----
  {
    const float* wr_ = Wout + (size_t)el * 1024 + dir * 512 + eks * 32;
    const float* hb2 = hbuf + 131072 + dir * 65536 + (size_t)bb * 512 + eks * 32;
    float4 wv[8], hv[8];
    #pragma unroll
    for (int q = 0; q < 8; ++q) wv[q] = *(const float4*)&wr_[q * 4];
    #pragma unroll
    for (int q = 0; q < 8; ++q) hv[q] = *(const float4*)&hb2[q * 4];
    float emP = 0.f;
    #pragma unroll
    for (int q = 0; q < 8; ++q) {
      emP = fmaf(hv[q].x, wv[q].x, emP);
      emP = fmaf(hv[q].y, wv[q].y, emP);
      emP = fmaf(hv[q].z, wv[q].z, emP);
      emP = fmaf(hv[q].w, wv[q].w, emP);
    }
    em_red[eks * 32 + el] = emP;
    __syncthreads();
    if (tid < 32) {
      float p = 0.f;
      #pragma unroll
      for (int ksi = 0; ksi < 16; ++ksi) p += em_red[ksi * 32 + tid];
      const int te = dir ? 0 : (SEQ - 1);
      float* dst = em + ((size_t)bb * SEQ + te) * NL + tid;
      *dst = *dst + p;
    }
  }
}

__global__ __launch_bounds__(64)
void viterbi_kernel(const float* __restrict__ em, const int* __restrict__ mask,
                    const float* __restrict__ trans, float* __restrict__ out)
{
  __shared__ float tr[32][33];
  __shared__ float alpha[32];
  __shared__ float fin[32];
  __shared__ unsigned char bp[SEQ][32];
  __shared__ float path[SEQ];

  const int b = blockIdx.x, tid = threadIdx.x;
  for (int i = tid; i < 1024; i += 64) tr[i >> 5][i & 31] = trans[i];
  __syncthreads();

  const float* emB = em + (size_t)b * SEQ * NL;
  if (tid < 32) alpha[tid] = tr[BOSTAG][tid] + emB[tid];
  __syncthreads();

  for (int t = 1; t < SEQ; ++t) {
    float best = -INFINITY, e = 0.f;
    int arg = 0;
    if (tid < 32) {
      e = emB[t * NL + tid];
      #pragma unroll 4
      for (int p = 0; p < 32; ++p) {
        const float sc = (alpha[p] + tr[p][tid]) + e;  // np broadcast order
        if (sc > best) { best = sc; arg = p; }          // first-occurrence argmax
      }
    }
    __syncthreads();
    if (tid < 32) {
      const float m = (float)mask[b * SEQ + t];
      alpha[tid] = m * best + (1.f - m) * alpha[tid];
      bp[t][tid] = (unsigned char)arg;
    }
    __syncthreads();
  }

  if (tid < 32) fin[tid] = alpha[tid] + tr[tid][EOSTAG];
  __syncthreads();

  if (tid == 0) {
    float best = fin[0]; int tag = 0;
    for (int n = 1; n < 32; ++n) if (fin[n] > best) { best = fin[n]; tag = n; }
    out[b] = best;
    path[SEQ - 1] = (float)tag;
    for (int k = SEQ - 2; k >= 0; --k) {
      const int prev = bp[k + 1][tag];
      if (mask[b * SEQ + k + 1] > 0) tag = prev;
      path[k] = (float)tag;
    }
  }
  __syncthreads();
  for (int idx = tid; idx < SEQ; idx += 64)
    out[BATCH + (size_t)b * SEQ + idx] = path[idx];
}

extern "C" void kernel_launch(void* const* d_in, const int* in_sizes, int n_in,
                              void* d_out, int out_size, void* d_ws, size_t ws_size,
                              hipStream_t stream) {
  (void)in_sizes; (void)n_in; (void)out_size; (void)ws_size;
  const int*   x     = (const int*)d_in[0];
  const int*   mask  = (const int*)d_in[1];
  const float* emb   = (const float*)d_in[2];
  const float* Wih_f = (const float*)d_in[3];
  const float* Whh_f = (const float*)d_in[4];
  const float* bf    = (const float*)d_in[5];
  const float* Wih_b = (const float*)d_in[6];
  const float* Whh_b = (const float*)d_in[7];
  const float* bb    = (const float*)d_in[8];
  const float* Wout  = (const float*)d_in[9];
  const float* bout  = (const float*)d_in[10];
  const float* trans = (const float*)d_in[11];
  float* out  = (float*)d_out;
  float* hbuf = (float*)d_ws;                   // 262144 floats (1 MB)
  float* em   = hbuf + 262144;                  // 2097152 floats (8 MB)

  void* args[] = { (void*)&x, (void*)&emb,
                   (void*)&Wih_f, (void*)&Whh_f, (void*)&bf,
                   (void*)&Wih_b, (void*)&Whh_b, (void*)&bb,
                   (void*)&Wout, (void*)&bout,
                   (void*)&hbuf, (void*)&em };
  hipLaunchCooperativeKernel((void*)bilstm_coop, dim3(256), dim3(512), args, 0, stream);
  viterbi_kernel<<<dim3(128), dim3(64), 0, stream>>>(em, mask, trans, out);
}